// Round 5
// baseline (909.661 us; speedup 1.0000x reference)
//
#include <hip/hip_runtime.h>
#include <hip/hip_bf16.h>

#define T_STEPS 1000
#define BATCH   256
#define IN_C    32
#define HID     128
#define OUT_C   10

typedef __fp16 h2_t __attribute__((ext_vector_type(2)));

__device__ __forceinline__ float dot2f(uint32_t w, uint32_t a, float acc) {
#if __has_builtin(__builtin_amdgcn_fdot2)
  return __builtin_amdgcn_fdot2(__builtin_bit_cast(h2_t, a),
                                __builtin_bit_cast(h2_t, w), acc, false);
#else
  h2_t av = __builtin_bit_cast(h2_t, a);
  h2_t wv = __builtin_bit_cast(h2_t, w);
  return acc + (float)av[0] * (float)wv[0] + (float)av[1] * (float)wv[1];
#endif
}

__device__ __forceinline__ uint32_t pack_f16(float a, float b) {
#if __has_builtin(__builtin_amdgcn_cvt_pkrtz)
  auto p = __builtin_amdgcn_cvt_pkrtz(a, b);
  return __builtin_bit_cast(uint32_t, p);
#else
  h2_t p; p[0] = (__fp16)a; p[1] = (__fp16)b;
  return __builtin_bit_cast(uint32_t, p);
#endif
}

// quad_perm DPP lane swaps (VALU-speed)
__device__ __forceinline__ float dpp_xor1(float x) {   // lane ^= 1 within quad
  return __builtin_bit_cast(float, __builtin_amdgcn_update_dpp(
      0, __builtin_bit_cast(int, x), 0xB1, 0xF, 0xF, true));
}
__device__ __forceinline__ float dpp_xor2(float x) {   // lane ^= 2 within quad
  return __builtin_bit_cast(float, __builtin_amdgcn_update_dpp(
      0, __builtin_bit_cast(int, x), 0x4E, 0xF, 0xF, true));
}

__device__ __forceinline__ float fast_tanh(float x) {
  float a = x * 2.88539008178f;                 // 2*log2(e)*x
  a = fminf(fmaxf(a, -126.f), 126.f);
#if __has_builtin(__builtin_amdgcn_exp2f)
  float t = __builtin_amdgcn_exp2f(a);
#else
  float t = exp2f(a);
#endif
#if __has_builtin(__builtin_amdgcn_rcpf)
  float r = __builtin_amdgcn_rcpf(t + 1.f);
#else
  float r = 1.f / (t + 1.f);
#endif
  return (t - 1.f) * r;
}

// block barrier WITHOUT draining vmcnt: dW prefetch stays in flight.
#define WG_BARRIER() asm volatile("s_waitcnt lgkmcnt(0)\n\ts_barrier" ::: "memory")

// ---------------- kernel 0: dt = max(min(diff(times)), 0.001) ----------------
__global__ __launch_bounds__(256) void k_dt(const float* __restrict__ times,
                                            float* __restrict__ dtb) {
  __shared__ float smin[256];
  int tid = threadIdx.x;
  float m = 1e30f;
  for (int t = tid; t < T_STEPS - 1; t += 256)
    m = fminf(m, times[t + 1] - times[t]);
  smin[tid] = m;
  __syncthreads();
  for (int off = 128; off > 0; off >>= 1) {
    if (tid < off) smin[tid] = fminf(smin[tid], smin[tid + off]);
    __syncthreads();
  }
  if (tid == 0) {
    float dt = fmaxf(smin[0], 0.001f);
    dtb[0] = dt;
    dtb[1] = sqrtf(dt);
  }
}

// ---------------- kernel 1: Euler-Maruyama SDE per trajectory ----------------
// block b = trajectory; 1024 threads (16 waves -> 4 per SIMD):
//   q = tid&3 (k-quarter), s = (tid>>2)&1 (f vs g), j = tid>>3 (hidden unit)
// Thread: 32-long quarter-dot (16 v_dot2); quarters combined via 2 quad DPPs.
// LDS: z chunks linear (read 4c+q: 16 disjoint banks/instr, broadcast over j);
// h chunks interleaved 2m+s (group (s,q) hits banks 8q+4s..+3: all 32 banks).
__global__ __launch_bounds__(1024) void k_sde(
    const float* __restrict__ x0, const float* __restrict__ dW,
    const int* __restrict__ fidx,
    const float* __restrict__ Winit, const float* __restrict__ binit,
    const float* __restrict__ Wf1, const float* __restrict__ bf1,
    const float* __restrict__ Wf2, const float* __restrict__ bf2,
    const float* __restrict__ Wg1, const float* __restrict__ bg1,
    const float* __restrict__ Wg2, const float* __restrict__ bg2,
    const float* __restrict__ dtb, float* __restrict__ zf) {
  const int b = blockIdx.x;
  const int tid = threadIdx.x;
  const int q = tid & 3;
  const int s = (tid >> 2) & 1;
  const int j = tid >> 3;

  __shared__ alignas(16) uint4 zp4[16];   // z: 128 f16, chunk m = elems 8m..8m+7
  __shared__ alignas(16) uint4 hb4[32];   // h: chunk index 2m+s (m as above)

  const float dt  = dtb[0];
  const float sdt = dtb[1];

  // weight-stationary: thread's k-set = chunks {4c+q}, c=0..3 (32 elems)
  const float* M1 = s ? Wg1 : Wf1;
  const float* M2 = s ? Wg2 : Wf2;
  uint32_t wA[16], wB[16];
#pragma unroll
  for (int c = 0; c < 4; ++c) {
    int k0 = (4 * c + q) * 8;
#pragma unroll
    for (int d = 0; d < 4; ++d) {
      wA[4 * c + d] = pack_f16(M1[(k0 + 2 * d) * HID + j], M1[(k0 + 2 * d + 1) * HID + j]);
      wB[4 * c + d] = pack_f16(M2[(k0 + 2 * d) * HID + j], M2[(k0 + 2 * d + 1) * HID + j]);
    }
  }
  const float bias1 = q ? 0.f : (s ? bg1 : bf1)[j];
  const float bias2 = q ? 0.f : (s ? bg2 : bf2)[j];

  // z0 = x0 @ Winit + binit (replicated across the 8 (s,q) lanes of j)
  float z = binit[j];
#pragma unroll
  for (int i = 0; i < IN_C; ++i)
    z = fmaf(x0[b * IN_C + i], Winit[i * HID + j], z);

  __fp16* zh = (__fp16*)zp4;
  if ((tid & 7) == 0) zh[j] = (__fp16)z;

  const int nsteps = fidx[b];  // in [0, T-1]

  const float* dwp = dW + (size_t)b * HID + j;
  const size_t sBH = (size_t)BATCH * HID;
  float dwA = dwp[0];
  float dwB = dwp[sBH];
  float dwC = dwp[2 * sBH];

  __fp16* hh = (__fp16*)hb4;
  const int hidx = 16 * (j >> 3) + 8 * s + (j & 7);  // fp16 slot for h[j] of mlp s

  WG_BARRIER();

  for (int t = 0; t < nsteps; ++t) {
    float dwv = dwA;
    dwA = dwB;
    dwB = dwC;
    int tn = t + 3;
    if (tn > T_STEPS - 2) tn = T_STEPS - 2;
    dwC = dwp[(size_t)tn * sBH];  // prefetch 3 ahead, survives barriers

    // layer 1 quarter-dot
    float a0 = bias1, a1 = 0.f, a2 = 0.f, a3 = 0.f;
#pragma unroll
    for (int c = 0; c < 4; ++c) {
      uint4 v = zp4[4 * c + q];
      a0 = dot2f(wA[4 * c + 0], v.x, a0);
      a1 = dot2f(wA[4 * c + 1], v.y, a1);
      a2 = dot2f(wA[4 * c + 2], v.z, a2);
      a3 = dot2f(wA[4 * c + 3], v.w, a3);
    }
    float p = (a0 + a1) + (a2 + a3);
    p += dpp_xor1(p);
    p += dpp_xor2(p);                   // full quad sum in every lane
    float h1 = fast_tanh(p);
    if (q == 0) hh[hidx] = (__fp16)h1;
    WG_BARRIER();

    // layer 2 quarter-dot
    float q0 = bias2, q1 = 0.f, q2 = 0.f, q3 = 0.f;
#pragma unroll
    for (int c = 0; c < 4; ++c) {
      uint4 v = hb4[2 * (4 * c + q) + s];
      q0 = dot2f(wB[4 * c + 0], v.x, q0);
      q1 = dot2f(wB[4 * c + 1], v.y, q1);
      q2 = dot2f(wB[4 * c + 2], v.z, q2);
      q3 = dot2f(wB[4 * c + 3], v.w, q3);
    }
    float qs = (q0 + q1) + (q2 + q3);
    qs += dpp_xor1(qs);
    qs += dpp_xor2(qs);
    float tg  = fast_tanh(qs);          // meaningful for s=1 (g tanh-bounded)
    float val = s ? tg : qs;
    float oth = __shfl_xor(val, 4, 64); // exchange f <-> g (lane^4)
    float fv = s ? oth : val;
    float gv = s ? val : oth;
    z = fmaf(fv, dt, fmaf(gv, sdt * dwv, z));
    if ((tid & 7) == 0) zh[j] = (__fp16)z;
    WG_BARRIER();
  }

  if ((tid & 7) == 0) zf[b * HID + j] = z;
}

// ---------------- kernel 2a: h = zf @ W1 + b1, per-block column partial stats --
__global__ __launch_bounds__(256) void k_ro1(const float* __restrict__ zf,
                                             const float* __restrict__ W1,
                                             const float* __restrict__ b1,
                                             float* __restrict__ hbuf,
                                             float* __restrict__ p1,
                                             float* __restrict__ p2) {
  int blk = blockIdx.x;  // 32 blocks x 8 rows
  int tid = threadIdx.x;
  int j = tid & 127, half = tid >> 7;
  int b0 = blk * 8 + half * 4;
  float acc[4];
  float bj = b1[j];
#pragma unroll
  for (int r = 0; r < 4; ++r) acc[r] = bj;
  for (int i = 0; i < HID; ++i) {
    float w = W1[i * HID + j];
#pragma unroll
    for (int r = 0; r < 4; ++r)
      acc[r] = fmaf(zf[(b0 + r) * HID + i], w, acc[r]);
  }
  float s1 = 0.f, s2 = 0.f;
#pragma unroll
  for (int r = 0; r < 4; ++r) {
    hbuf[(b0 + r) * HID + j] = acc[r];
    s1 += acc[r];
    s2 = fmaf(acc[r], acc[r], s2);
  }
  __shared__ float q1[2][128], q2[2][128];
  q1[half][j] = s1;
  q2[half][j] = s2;
  __syncthreads();
  if (tid < 128) {
    p1[blk * HID + tid] = q1[0][tid] + q1[1][tid];
    p2[blk * HID + tid] = q2[0][tid] + q2[1][tid];
  }
}

// ---------------- kernel 2b: BN + ReLU + W2 readout ---------------------------
__global__ __launch_bounds__(1024) void k_ro2(
    const float* __restrict__ hbuf, const float* __restrict__ p1,
    const float* __restrict__ p2, const float* __restrict__ gamma,
    const float* __restrict__ beta, const float* __restrict__ W2,
    const float* __restrict__ b2, float* __restrict__ out) {
  __shared__ float sa[128], sc[128];
  int tid = threadIdx.x;
  if (tid < 128) {
    float m = 0.f, q = 0.f;
    for (int blk = 0; blk < 32; ++blk) {
      m += p1[blk * HID + tid];
      q += p2[blk * HID + tid];
    }
    m *= (1.f / BATCH);
    q *= (1.f / BATCH);
    float var = q - m * m;
    float r = rsqrtf(var + 1e-5f);
    float a = gamma[tid] * r;
    sa[tid] = a;
    sc[tid] = beta[tid] - m * a;
  }
  __syncthreads();
  for (int idx = tid; idx < BATCH * OUT_C; idx += 1024) {
    int b = idx / OUT_C;
    int o = idx - b * OUT_C;
    float acc = b2[o];
    for (int jj = 0; jj < HID; ++jj) {
      float hn = fmaxf(fmaf(sa[jj], hbuf[b * HID + jj], sc[jj]), 0.f);
      acc = fmaf(hn, W2[jj * OUT_C + o], acc);
    }
    out[idx] = acc;
  }
}

extern "C" void kernel_launch(void* const* d_in, const int* in_sizes, int n_in,
                              void* d_out, int out_size, void* d_ws, size_t ws_size,
                              hipStream_t stream) {
  const float* times = (const float*)d_in[0];
  const float* x0    = (const float*)d_in[1];
  const float* dW    = (const float*)d_in[2];
  const int*   fidx  = (const int*)d_in[3];
  const float* Winit = (const float*)d_in[4];
  const float* binit = (const float*)d_in[5];
  const float* Wf1 = (const float*)d_in[6];
  const float* bf1 = (const float*)d_in[7];
  const float* Wf2 = (const float*)d_in[8];
  const float* bf2 = (const float*)d_in[9];
  const float* Wg1 = (const float*)d_in[10];
  const float* bg1 = (const float*)d_in[11];
  const float* Wg2 = (const float*)d_in[12];
  const float* bg2 = (const float*)d_in[13];
  const float* W1  = (const float*)d_in[14];
  const float* b1  = (const float*)d_in[15];
  const float* gamma = (const float*)d_in[16];
  const float* beta  = (const float*)d_in[17];
  const float* W2  = (const float*)d_in[18];
  const float* b2  = (const float*)d_in[19];

  float* wsf  = (float*)d_ws;
  float* dtb  = wsf;                       // 2 floats (+pad)
  float* zf   = wsf + 16;                  // 256*128
  float* hbuf = zf + BATCH * HID;          // 256*128
  float* p1   = hbuf + BATCH * HID;        // 32*128
  float* p2   = p1 + 32 * HID;             // 32*128
  float* out  = (float*)d_out;

  hipLaunchKernelGGL(k_dt, dim3(1), dim3(256), 0, stream, times, dtb);
  hipLaunchKernelGGL(k_sde, dim3(BATCH), dim3(1024), 0, stream, x0, dW, fidx,
                     Winit, binit, Wf1, bf1, Wf2, bf2, Wg1, bg1, Wg2, bg2, dtb,
                     zf);
  hipLaunchKernelGGL(k_ro1, dim3(32), dim3(256), 0, stream, zf, W1, b1, hbuf,
                     p1, p2);
  hipLaunchKernelGGL(k_ro2, dim3(1), dim3(1024), 0, stream, hbuf, p1, p2, gamma,
                     beta, W2, b2, out);
}

// Round 6
// 864.607 us; speedup vs baseline: 1.0521x; 1.0521x over previous
//
#include <hip/hip_runtime.h>
#include <hip/hip_bf16.h>

#define T_STEPS 1000
#define BATCH   256
#define IN_C    32
#define HID     128
#define OUT_C   10

typedef __fp16 h2_t __attribute__((ext_vector_type(2)));

__device__ __forceinline__ float dot2f(uint32_t w, uint32_t a, float acc) {
#if __has_builtin(__builtin_amdgcn_fdot2)
  return __builtin_amdgcn_fdot2(__builtin_bit_cast(h2_t, a),
                                __builtin_bit_cast(h2_t, w), acc, false);
#else
  h2_t av = __builtin_bit_cast(h2_t, a);
  h2_t wv = __builtin_bit_cast(h2_t, w);
  return acc + (float)av[0] * (float)wv[0] + (float)av[1] * (float)wv[1];
#endif
}

__device__ __forceinline__ uint32_t pack_f16(float a, float b) {
#if __has_builtin(__builtin_amdgcn_cvt_pkrtz)
  auto p = __builtin_amdgcn_cvt_pkrtz(a, b);
  return __builtin_bit_cast(uint32_t, p);
#else
  h2_t p; p[0] = (__fp16)a; p[1] = (__fp16)b;
  return __builtin_bit_cast(uint32_t, p);
#endif
}

// quad_perm DPP lane swaps (VALU-speed)
__device__ __forceinline__ float dpp_xor1(float x) {   // lane ^= 1 within quad
  return __builtin_bit_cast(float, __builtin_amdgcn_update_dpp(
      0, __builtin_bit_cast(int, x), 0xB1, 0xF, 0xF, true));
}
__device__ __forceinline__ float dpp_xor2(float x) {   // lane ^= 2 within quad
  return __builtin_bit_cast(float, __builtin_amdgcn_update_dpp(
      0, __builtin_bit_cast(int, x), 0x4E, 0xF, 0xF, true));
}

__device__ __forceinline__ float fast_tanh(float x) {
  float a = x * 2.88539008178f;                 // 2*log2(e)*x
  a = fminf(fmaxf(a, -126.f), 126.f);
#if __has_builtin(__builtin_amdgcn_exp2f)
  float t = __builtin_amdgcn_exp2f(a);
#else
  float t = exp2f(a);
#endif
#if __has_builtin(__builtin_amdgcn_rcpf)
  float r = __builtin_amdgcn_rcpf(t + 1.f);
#else
  float r = 1.f / (t + 1.f);
#endif
  return (t - 1.f) * r;
}

// block barrier WITHOUT draining vmcnt: dW prefetch stays in flight.
#define WG_BARRIER() asm volatile("s_waitcnt lgkmcnt(0)\n\ts_barrier" ::: "memory")

// padded f16-slot index: element e of a 128-f16 vector stored as 16 uint4
// chunks with one 16B pad after chunk 7 (breaks the 128B bank alias).
__device__ __forceinline__ int padslot(int e) { return e + ((e >> 6) << 3); }

// ---------------- kernel 0: dt = max(min(diff(times)), 0.001) ----------------
__global__ __launch_bounds__(256) void k_dt(const float* __restrict__ times,
                                            float* __restrict__ dtb) {
  __shared__ float smin[256];
  int tid = threadIdx.x;
  float m = 1e30f;
  for (int t = tid; t < T_STEPS - 1; t += 256)
    m = fminf(m, times[t + 1] - times[t]);
  smin[tid] = m;
  __syncthreads();
  for (int off = 128; off > 0; off >>= 1) {
    if (tid < off) smin[tid] = fminf(smin[tid], smin[tid + off]);
    __syncthreads();
  }
  if (tid == 0) {
    float dt = fmaxf(smin[0], 0.001f);
    dtb[0] = dt;
    dtb[1] = sqrtf(dt);
  }
}

// ---------------- kernel 1: Euler-Maruyama SDE per trajectory ----------------
// block b = trajectory; 512 threads (8 waves -> 2 per SIMD):
//   q = tid&3 (k-quarter), s = (tid>>2)&1 (f vs g), j2 = tid>>3 (column pair)
// Thread computes columns {j2, j2+64} of MLP s over k in [32q,32q+32):
// one z/h chunk load feeds BOTH columns -> LDS read instrs halved vs 1-col.
// k-combine: quad-local (q = lane bits 0-1) via dpp_xor1+xor2.
// f<->g: one shfl_xor(4) per step, exchanged PRE-tanh (1 tanh/thread/phase).
// LDS: padded chunk layout idx(m)=m+(m>>3); h_g at +288B => all 8 (s,q)
// read groups on disjoint banks.
__global__ __launch_bounds__(512) void k_sde(
    const float* __restrict__ x0, const float* __restrict__ dW,
    const int* __restrict__ fidx,
    const float* __restrict__ Winit, const float* __restrict__ binit,
    const float* __restrict__ Wf1, const float* __restrict__ bf1,
    const float* __restrict__ Wf2, const float* __restrict__ bf2,
    const float* __restrict__ Wg1, const float* __restrict__ bg1,
    const float* __restrict__ Wg2, const float* __restrict__ bg2,
    const float* __restrict__ dtb, float* __restrict__ zf) {
  const int b = blockIdx.x;
  const int tid = threadIdx.x;
  const int q = tid & 3;
  const int s = (tid >> 2) & 1;
  const int j2 = tid >> 3;

  __shared__ alignas(16) uint4 zb[17];   // z: chunk m at idx m+(m>>3)
  __shared__ alignas(16) uint4 hb[35];   // h_f at idx(m); h_g at 18+idx(m)

  const float dt  = dtb[0];
  const float sdt = dtb[1];

  // weight-stationary: cols {j2, j2+64} of MLP s, k in [32q, 32q+32)
  const float* M1 = s ? Wg1 : Wf1;
  const float* M2 = s ? Wg2 : Wf2;
  uint32_t wA0[16], wA1[16], wB0[16], wB1[16];
#pragma unroll
  for (int c = 0; c < 4; ++c) {
#pragma unroll
    for (int d = 0; d < 4; ++d) {
      int k = 32 * q + 8 * c + 2 * d;
      wA0[4 * c + d] = pack_f16(M1[k * HID + j2],      M1[(k + 1) * HID + j2]);
      wA1[4 * c + d] = pack_f16(M1[k * HID + j2 + 64], M1[(k + 1) * HID + j2 + 64]);
      wB0[4 * c + d] = pack_f16(M2[k * HID + j2],      M2[(k + 1) * HID + j2]);
      wB1[4 * c + d] = pack_f16(M2[k * HID + j2 + 64], M2[(k + 1) * HID + j2 + 64]);
    }
  }
  const float* B1 = s ? bg1 : bf1;
  const float* B2 = s ? bg2 : bf2;
  const float b1c0 = q ? 0.f : B1[j2];
  const float b1c1 = q ? 0.f : B1[j2 + 64];
  const float b2c0 = q ? 0.f : B2[j2];
  const float b2c1 = q ? 0.f : B2[j2 + 64];

  // z0 for my column (q==0 lanes of each (j2,s) own one z element)
  const int mycol = s ? j2 + 64 : j2;
  float z = binit[mycol];
#pragma unroll
  for (int i = 0; i < IN_C; ++i)
    z = fmaf(x0[b * IN_C + i], Winit[i * HID + mycol], z);

  __fp16* zh = (__fp16*)zb;
  __fp16* hh = (__fp16*)hb;
  if (q == 0) zh[padslot(mycol)] = (__fp16)z;

  const int nsteps = fidx[b];  // in [0, T-1]

  const float* dwp = dW + (size_t)b * HID + mycol;
  const size_t sBH = (size_t)BATCH * HID;
  float dwA = 0.f, dwB = 0.f, dwC = 0.f;
  if (q == 0) { dwA = dwp[0]; dwB = dwp[sBH]; dwC = dwp[2 * sBH]; }

  // per-thread read bases (chunks 4q..4q+3, padded index)
  const uint4* zr = zb + 4 * q + (q >> 1);
  const uint4* hr = hb + (s ? 18 : 0) + 4 * q + (q >> 1);
  const int hwbase = s ? 144 : 0;  // __fp16 units (18 uint4)

  WG_BARRIER();

  for (int t = 0; t < nsteps; ++t) {
    float dwv = dwA;
    if (q == 0) {
      dwA = dwB;
      dwB = dwC;
      int tn = t + 3;
      if (tn > T_STEPS - 2) tn = T_STEPS - 2;
      dwC = dwp[(size_t)tn * sBH];  // prefetch 3 ahead, survives barriers
    }

    // ---- phase 1: layer 1, quarter-k, two columns off the same loads ----
    float a0 = b1c0, a1 = 0.f, a2 = 0.f, a3 = 0.f;
    float c0 = b1c1, c1 = 0.f, c2 = 0.f, c3 = 0.f;
#pragma unroll
    for (int c = 0; c < 4; ++c) {
      uint4 v = zr[c];
      a0 = dot2f(wA0[4 * c + 0], v.x, a0);
      a1 = dot2f(wA0[4 * c + 1], v.y, a1);
      a2 = dot2f(wA0[4 * c + 2], v.z, a2);
      a3 = dot2f(wA0[4 * c + 3], v.w, a3);
      c0 = dot2f(wA1[4 * c + 0], v.x, c0);
      c1 = dot2f(wA1[4 * c + 1], v.y, c1);
      c2 = dot2f(wA1[4 * c + 2], v.z, c2);
      c3 = dot2f(wA1[4 * c + 3], v.w, c3);
    }
    float p0 = (a0 + a1) + (a2 + a3);
    float p1 = (c0 + c1) + (c2 + c3);
    p0 += dpp_xor1(p0); p0 += dpp_xor2(p0);   // full 128-k sum, all quad lanes
    p1 += dpp_xor1(p1); p1 += dpp_xor2(p1);
    if (q < 2) {
      float tv = fast_tanh(q ? p1 : p0);
      int e = q ? j2 + 64 : j2;
      hh[hwbase + padslot(e)] = (__fp16)tv;
    }
    WG_BARRIER();

    // ---- phase 2: layer 2, quarter-k of h_s, two columns ----
    float e0 = b2c0, e1 = 0.f, e2 = 0.f, e3 = 0.f;
    float f0 = b2c1, f1 = 0.f, f2 = 0.f, f3 = 0.f;
#pragma unroll
    for (int c = 0; c < 4; ++c) {
      uint4 v = hr[c];
      e0 = dot2f(wB0[4 * c + 0], v.x, e0);
      e1 = dot2f(wB0[4 * c + 1], v.y, e1);
      e2 = dot2f(wB0[4 * c + 2], v.z, e2);
      e3 = dot2f(wB0[4 * c + 3], v.w, e3);
      f0 = dot2f(wB1[4 * c + 0], v.x, f0);
      f1 = dot2f(wB1[4 * c + 1], v.y, f1);
      f2 = dot2f(wB1[4 * c + 2], v.z, f2);
      f3 = dot2f(wB1[4 * c + 3], v.w, f3);
    }
    float o0 = (e0 + e1) + (e2 + e3);   // col j2
    float o1 = (f0 + f1) + (f2 + f3);   // col j2+64
    o0 += dpp_xor1(o0); o0 += dpp_xor2(o0);
    o1 += dpp_xor1(o1); o1 += dpp_xor2(o1);
    // exchange pre-tanh: s=0 sends f-preact[j2+64], gets g-preact[j2];
    //                    s=1 sends g-preact[j2],    gets f-preact[j2+64]
    float send = s ? o0 : o1;
    float recv = __shfl_xor(send, 4, 64);
    if (q == 0) {
      float fv = s ? recv : o0;                 // f output (no outer tanh)
      float gv = fast_tanh(s ? o1 : recv);      // g output (tanh-bounded)
      z = fmaf(fv, dt, fmaf(gv, sdt * dwv, z));
      zh[padslot(mycol)] = (__fp16)z;
    }
    WG_BARRIER();
  }

  if (q == 0) zf[b * HID + mycol] = z;
}

// ---------------- kernel 2a: h = zf @ W1 + b1, per-block column partial stats --
__global__ __launch_bounds__(256) void k_ro1(const float* __restrict__ zf,
                                             const float* __restrict__ W1,
                                             const float* __restrict__ b1,
                                             float* __restrict__ hbuf,
                                             float* __restrict__ p1,
                                             float* __restrict__ p2) {
  int blk = blockIdx.x;  // 32 blocks x 8 rows
  int tid = threadIdx.x;
  int j = tid & 127, half = tid >> 7;
  int b0 = blk * 8 + half * 4;
  float acc[4];
  float bj = b1[j];
#pragma unroll
  for (int r = 0; r < 4; ++r) acc[r] = bj;
  for (int i = 0; i < HID; ++i) {
    float w = W1[i * HID + j];
#pragma unroll
    for (int r = 0; r < 4; ++r)
      acc[r] = fmaf(zf[(b0 + r) * HID + i], w, acc[r]);
  }
  float s1 = 0.f, s2 = 0.f;
#pragma unroll
  for (int r = 0; r < 4; ++r) {
    hbuf[(b0 + r) * HID + j] = acc[r];
    s1 += acc[r];
    s2 = fmaf(acc[r], acc[r], s2);
  }
  __shared__ float q1[2][128], q2[2][128];
  q1[half][j] = s1;
  q2[half][j] = s2;
  __syncthreads();
  if (tid < 128) {
    p1[blk * HID + tid] = q1[0][tid] + q1[1][tid];
    p2[blk * HID + tid] = q2[0][tid] + q2[1][tid];
  }
}

// ---------------- kernel 2b: BN + ReLU + W2 readout ---------------------------
__global__ __launch_bounds__(1024) void k_ro2(
    const float* __restrict__ hbuf, const float* __restrict__ p1,
    const float* __restrict__ p2, const float* __restrict__ gamma,
    const float* __restrict__ beta, const float* __restrict__ W2,
    const float* __restrict__ b2, float* __restrict__ out) {
  __shared__ float sa[128], sc[128];
  int tid = threadIdx.x;
  if (tid < 128) {
    float m = 0.f, q = 0.f;
    for (int blk = 0; blk < 32; ++blk) {
      m += p1[blk * HID + tid];
      q += p2[blk * HID + tid];
    }
    m *= (1.f / BATCH);
    q *= (1.f / BATCH);
    float var = q - m * m;
    float r = rsqrtf(var + 1e-5f);
    float a = gamma[tid] * r;
    sa[tid] = a;
    sc[tid] = beta[tid] - m * a;
  }
  __syncthreads();
  for (int idx = tid; idx < BATCH * OUT_C; idx += 1024) {
    int b = idx / OUT_C;
    int o = idx - b * OUT_C;
    float acc = b2[o];
    for (int jj = 0; jj < HID; ++jj) {
      float hn = fmaxf(fmaf(sa[jj], hbuf[b * HID + jj], sc[jj]), 0.f);
      acc = fmaf(hn, W2[jj * OUT_C + o], acc);
    }
    out[idx] = acc;
  }
}

extern "C" void kernel_launch(void* const* d_in, const int* in_sizes, int n_in,
                              void* d_out, int out_size, void* d_ws, size_t ws_size,
                              hipStream_t stream) {
  const float* times = (const float*)d_in[0];
  const float* x0    = (const float*)d_in[1];
  const float* dW    = (const float*)d_in[2];
  const int*   fidx  = (const int*)d_in[3];
  const float* Winit = (const float*)d_in[4];
  const float* binit = (const float*)d_in[5];
  const float* Wf1 = (const float*)d_in[6];
  const float* bf1 = (const float*)d_in[7];
  const float* Wf2 = (const float*)d_in[8];
  const float* bf2 = (const float*)d_in[9];
  const float* Wg1 = (const float*)d_in[10];
  const float* bg1 = (const float*)d_in[11];
  const float* Wg2 = (const float*)d_in[12];
  const float* bg2 = (const float*)d_in[13];
  const float* W1  = (const float*)d_in[14];
  const float* b1  = (const float*)d_in[15];
  const float* gamma = (const float*)d_in[16];
  const float* beta  = (const float*)d_in[17];
  const float* W2  = (const float*)d_in[18];
  const float* b2  = (const float*)d_in[19];

  float* wsf  = (float*)d_ws;
  float* dtb  = wsf;                       // 2 floats (+pad)
  float* zf   = wsf + 16;                  // 256*128
  float* hbuf = zf + BATCH * HID;          // 256*128
  float* p1   = hbuf + BATCH * HID;        // 32*128
  float* p2   = p1 + 32 * HID;             // 32*128
  float* out  = (float*)d_out;

  hipLaunchKernelGGL(k_dt, dim3(1), dim3(256), 0, stream, times, dtb);
  hipLaunchKernelGGL(k_sde, dim3(BATCH), dim3(512), 0, stream, x0, dW, fidx,
                     Winit, binit, Wf1, bf1, Wf2, bf2, Wg1, bg1, Wg2, bg2, dtb,
                     zf);
  hipLaunchKernelGGL(k_ro1, dim3(32), dim3(256), 0, stream, zf, W1, b1, hbuf,
                     p1, p2);
  hipLaunchKernelGGL(k_ro2, dim3(1), dim3(1024), 0, stream, hbuf, p1, p2, gamma,
                     beta, W2, b2, out);
}

// Round 7
// 717.101 us; speedup vs baseline: 1.2685x; 1.2057x over previous
//
#include <hip/hip_runtime.h>
#include <hip/hip_bf16.h>

#define T_STEPS 1000
#define BATCH   256
#define IN_C    32
#define HID     128
#define OUT_C   10

typedef __fp16 h2_t __attribute__((ext_vector_type(2)));

__device__ __forceinline__ float dot2f(uint32_t w, uint32_t a, float acc) {
#if __has_builtin(__builtin_amdgcn_fdot2)
  return __builtin_amdgcn_fdot2(__builtin_bit_cast(h2_t, a),
                                __builtin_bit_cast(h2_t, w), acc, false);
#else
  h2_t av = __builtin_bit_cast(h2_t, a);
  h2_t wv = __builtin_bit_cast(h2_t, w);
  return acc + (float)av[0] * (float)wv[0] + (float)av[1] * (float)wv[1];
#endif
}

__device__ __forceinline__ uint32_t pack_f16(float a, float b) {
#if __has_builtin(__builtin_amdgcn_cvt_pkrtz)
  auto p = __builtin_amdgcn_cvt_pkrtz(a, b);
  return __builtin_bit_cast(uint32_t, p);
#else
  h2_t p; p[0] = (__fp16)a; p[1] = (__fp16)b;
  return __builtin_bit_cast(uint32_t, p);
#endif
}

// quad_perm DPP lane swaps (VALU-speed, quad-local only)
__device__ __forceinline__ float dpp_xor1(float x) {   // lane ^= 1 within quad
  return __builtin_bit_cast(float, __builtin_amdgcn_update_dpp(
      0, __builtin_bit_cast(int, x), 0xB1, 0xF, 0xF, true));
}
__device__ __forceinline__ float dpp_xor2(float x) {   // lane ^= 2 within quad
  return __builtin_bit_cast(float, __builtin_amdgcn_update_dpp(
      0, __builtin_bit_cast(int, x), 0x4E, 0xF, 0xF, true));
}

__device__ __forceinline__ float fast_tanh(float x) {
  float a = x * 2.88539008178f;                 // 2*log2(e)*x
  a = fminf(fmaxf(a, -126.f), 126.f);
#if __has_builtin(__builtin_amdgcn_exp2f)
  float t = __builtin_amdgcn_exp2f(a);
#else
  float t = exp2f(a);
#endif
#if __has_builtin(__builtin_amdgcn_rcpf)
  float r = __builtin_amdgcn_rcpf(t + 1.f);
#else
  float r = 1.f / (t + 1.f);
#endif
  return (t - 1.f) * r;
}

// block barrier WITHOUT draining vmcnt: dW prefetch stays in flight.
#define WG_BARRIER() asm volatile("s_waitcnt lgkmcnt(0)\n\ts_barrier" ::: "memory")

// ---------------- kernel 0: dt = max(min(diff(times)), 0.001) ----------------
__global__ __launch_bounds__(256) void k_dt(const float* __restrict__ times,
                                            float* __restrict__ dtb) {
  __shared__ float smin[256];
  int tid = threadIdx.x;
  float m = 1e30f;
  for (int t = tid; t < T_STEPS - 1; t += 256)
    m = fminf(m, times[t + 1] - times[t]);
  smin[tid] = m;
  __syncthreads();
  for (int off = 128; off > 0; off >>= 1) {
    if (tid < off) smin[tid] = fminf(smin[tid], smin[tid + off]);
    __syncthreads();
  }
  if (tid == 0) {
    float dt = fmaxf(smin[0], 0.001f);
    dtb[0] = dt;
    dtb[1] = sqrtf(dt);
  }
}

// ---------------- kernel 1: Euler-Maruyama SDE per trajectory ----------------
// block b = trajectory; 512 threads (8 waves -> 2 per SIMD):
//   j = tid>>2 (hidden unit), s = (tid>>1)&1 (f vs g), h = tid&1 (k-half)
// R4 structure (best measured) + chain micro-cuts:
//   - all LDS writes unguarded (quad lanes write identical values to the same
//     address: benign dup-write, removes exec-mask dances from the chain)
//   - dws = sdt*dw hoisted off the z chain
//   - phase-2 f<->g exchange pre-tanh (dpp -> select -> tanh -> fma)
__global__ __launch_bounds__(512) void k_sde(
    const float* __restrict__ x0, const float* __restrict__ dW,
    const int* __restrict__ fidx,
    const float* __restrict__ Winit, const float* __restrict__ binit,
    const float* __restrict__ Wf1, const float* __restrict__ bf1,
    const float* __restrict__ Wf2, const float* __restrict__ bf2,
    const float* __restrict__ Wg1, const float* __restrict__ bg1,
    const float* __restrict__ Wg2, const float* __restrict__ bg2,
    const float* __restrict__ dtb, float* __restrict__ zf) {
  const int b = blockIdx.x;
  const int tid = threadIdx.x;
  const int j = tid >> 2;
  const int s = (tid >> 1) & 1;
  const int h = tid & 1;

  __shared__ alignas(16) uint4 zp4[16];   // z: 128 f16, chunk m = elems 8m..8m+7
  __shared__ alignas(16) uint4 hb[36];    // hf = hb[0..16), hg = hb[18..34)

  const float dt  = dtb[0];
  const float sdt = dtb[1];

  // weight-stationary packing, interleaved chunk order: read c pulls chunk
  // m=2c+h holding elements 8m..8m+7 (pairs 4m..4m+3)
  const float* M1 = s ? Wg1 : Wf1;
  const float* M2 = s ? Wg2 : Wf2;
  uint32_t wA[32], wB[32];
#pragma unroll
  for (int c = 0; c < 8; ++c) {
    int k0 = (2 * c + h) * 8;
#pragma unroll
    for (int d = 0; d < 4; ++d) {
      wA[4 * c + d] = pack_f16(M1[(k0 + 2 * d) * HID + j], M1[(k0 + 2 * d + 1) * HID + j]);
      wB[4 * c + d] = pack_f16(M2[(k0 + 2 * d) * HID + j], M2[(k0 + 2 * d + 1) * HID + j]);
    }
  }
  const float bias1 = h ? 0.f : (s ? bg1 : bf1)[j];
  const float bias2 = h ? 0.f : (s ? bg2 : bf2)[j];

  // z0 = x0 @ Winit + binit  (replicated across the 4 (s,h) lanes of j)
  float z = binit[j];
#pragma unroll
  for (int i = 0; i < IN_C; ++i)
    z = fmaf(x0[b * IN_C + i], Winit[i * HID + j], z);

  __fp16* zh = (__fp16*)zp4;
  zh[j] = (__fp16)z;   // all 4 quad lanes write the same value: benign

  const int nsteps = fidx[b];  // in [0, T-1]

  const float* dwp = dW + (size_t)b * HID + j;
  const size_t sBH = (size_t)BATCH * HID;
  float dwA = dwp[0];
  float dwB = dwp[sBH];
  float dwC = dwp[2 * sBH];

  const uint4* hp4 = hb + s * 18;
  __fp16* hdst     = (__fp16*)(hb + s * 18);

  WG_BARRIER();

  for (int t = 0; t < nsteps; ++t) {
    float dws = sdt * dwA;     // hoisted off the z chain
    dwA = dwB;
    dwB = dwC;
    int tn = t + 3;
    if (tn > T_STEPS - 2) tn = T_STEPS - 2;
    dwC = dwp[(size_t)tn * sBH];  // prefetch 3 ahead, survives barriers

    // ---- phase 1: layer 1 half-dot over interleaved k-chunks ----
    float a0 = bias1, a1 = 0.f, a2 = 0.f, a3 = 0.f;
#pragma unroll
    for (int c = 0; c < 8; ++c) {
      uint4 v = zp4[2 * c + h];
      a0 = dot2f(wA[4 * c + 0], v.x, a0);
      a1 = dot2f(wA[4 * c + 1], v.y, a1);
      a2 = dot2f(wA[4 * c + 2], v.z, a2);
      a3 = dot2f(wA[4 * c + 3], v.w, a3);
    }
    float p = (a0 + a1) + (a2 + a3);
    p += dpp_xor1(p);                   // combine k-halves (VALU DPP)
    float h1 = fast_tanh(p);
    hdst[j] = (__fp16)h1;               // both h-lanes write same value: benign
    WG_BARRIER();

    // ---- phase 2: layer 2 half-dot ----
    float q0 = bias2, q1 = 0.f, q2 = 0.f, q3 = 0.f;
#pragma unroll
    for (int c = 0; c < 8; ++c) {
      uint4 v = hp4[2 * c + h];
      q0 = dot2f(wB[4 * c + 0], v.x, q0);
      q1 = dot2f(wB[4 * c + 1], v.y, q1);
      q2 = dot2f(wB[4 * c + 2], v.z, q2);
      q3 = dot2f(wB[4 * c + 3], v.w, q3);
    }
    float qs = (q0 + q1) + (q2 + q3);
    qs += dpp_xor1(qs);                 // combine k-halves
    float oth = dpp_xor2(qs);           // f<->g pre-activation exchange
    float fpre = s ? oth : qs;          // f output (no outer tanh)
    float gpre = s ? qs : oth;          // g pre-activation (tanh-bounded)
    z = fmaf(fpre, dt, fmaf(fast_tanh(gpre), dws, z));
    zh[j] = (__fp16)z;                  // all 4 quad lanes write same value
    WG_BARRIER();
  }

  if ((tid & 3) == 0) zf[b * HID + j] = z;
}

// ---------------- kernel 2a: h = zf @ W1 + b1, per-block column partial stats --
__global__ __launch_bounds__(256) void k_ro1(const float* __restrict__ zf,
                                             const float* __restrict__ W1,
                                             const float* __restrict__ b1,
                                             float* __restrict__ hbuf,
                                             float* __restrict__ p1,
                                             float* __restrict__ p2) {
  int blk = blockIdx.x;  // 32 blocks x 8 rows
  int tid = threadIdx.x;
  int j = tid & 127, half = tid >> 7;
  int b0 = blk * 8 + half * 4;
  float acc[4];
  float bj = b1[j];
#pragma unroll
  for (int r = 0; r < 4; ++r) acc[r] = bj;
  for (int i = 0; i < HID; ++i) {
    float w = W1[i * HID + j];
#pragma unroll
    for (int r = 0; r < 4; ++r)
      acc[r] = fmaf(zf[(b0 + r) * HID + i], w, acc[r]);
  }
  float s1 = 0.f, s2 = 0.f;
#pragma unroll
  for (int r = 0; r < 4; ++r) {
    hbuf[(b0 + r) * HID + j] = acc[r];
    s1 += acc[r];
    s2 = fmaf(acc[r], acc[r], s2);
  }
  __shared__ float q1[2][128], q2[2][128];
  q1[half][j] = s1;
  q2[half][j] = s2;
  __syncthreads();
  if (tid < 128) {
    p1[blk * HID + tid] = q1[0][tid] + q1[1][tid];
    p2[blk * HID + tid] = q2[0][tid] + q2[1][tid];
  }
}

// ---------------- kernel 2b: BN + ReLU + W2 readout ---------------------------
__global__ __launch_bounds__(1024) void k_ro2(
    const float* __restrict__ hbuf, const float* __restrict__ p1,
    const float* __restrict__ p2, const float* __restrict__ gamma,
    const float* __restrict__ beta, const float* __restrict__ W2,
    const float* __restrict__ b2, float* __restrict__ out) {
  __shared__ float sa[128], sc[128];
  int tid = threadIdx.x;
  if (tid < 128) {
    float m = 0.f, q = 0.f;
    for (int blk = 0; blk < 32; ++blk) {
      m += p1[blk * HID + tid];
      q += p2[blk * HID + tid];
    }
    m *= (1.f / BATCH);
    q *= (1.f / BATCH);
    float var = q - m * m;
    float r = rsqrtf(var + 1e-5f);
    float a = gamma[tid] * r;
    sa[tid] = a;
    sc[tid] = beta[tid] - m * a;
  }
  __syncthreads();
  for (int idx = tid; idx < BATCH * OUT_C; idx += 1024) {
    int b = idx / OUT_C;
    int o = idx - b * OUT_C;
    float acc = b2[o];
    for (int jj = 0; jj < HID; ++jj) {
      float hn = fmaxf(fmaf(sa[jj], hbuf[b * HID + jj], sc[jj]), 0.f);
      acc = fmaf(hn, W2[jj * OUT_C + o], acc);
    }
    out[idx] = acc;
  }
}

extern "C" void kernel_launch(void* const* d_in, const int* in_sizes, int n_in,
                              void* d_out, int out_size, void* d_ws, size_t ws_size,
                              hipStream_t stream) {
  const float* times = (const float*)d_in[0];
  const float* x0    = (const float*)d_in[1];
  const float* dW    = (const float*)d_in[2];
  const int*   fidx  = (const int*)d_in[3];
  const float* Winit = (const float*)d_in[4];
  const float* binit = (const float*)d_in[5];
  const float* Wf1 = (const float*)d_in[6];
  const float* bf1 = (const float*)d_in[7];
  const float* Wf2 = (const float*)d_in[8];
  const float* bf2 = (const float*)d_in[9];
  const float* Wg1 = (const float*)d_in[10];
  const float* bg1 = (const float*)d_in[11];
  const float* Wg2 = (const float*)d_in[12];
  const float* bg2 = (const float*)d_in[13];
  const float* W1  = (const float*)d_in[14];
  const float* b1  = (const float*)d_in[15];
  const float* gamma = (const float*)d_in[16];
  const float* beta  = (const float*)d_in[17];
  const float* W2  = (const float*)d_in[18];
  const float* b2  = (const float*)d_in[19];

  float* wsf  = (float*)d_ws;
  float* dtb  = wsf;                       // 2 floats (+pad)
  float* zf   = wsf + 16;                  // 256*128
  float* hbuf = zf + BATCH * HID;          // 256*128
  float* p1   = hbuf + BATCH * HID;        // 32*128
  float* p2   = p1 + 32 * HID;             // 32*128
  float* out  = (float*)d_out;

  hipLaunchKernelGGL(k_dt, dim3(1), dim3(256), 0, stream, times, dtb);
  hipLaunchKernelGGL(k_sde, dim3(BATCH), dim3(512), 0, stream, x0, dW, fidx,
                     Winit, binit, Wf1, bf1, Wf2, bf2, Wg1, bg1, Wg2, bg2, dtb,
                     zf);
  hipLaunchKernelGGL(k_ro1, dim3(32), dim3(256), 0, stream, zf, W1, b1, hbuf,
                     p1, p2);
  hipLaunchKernelGGL(k_ro2, dim3(1), dim3(1024), 0, stream, hbuf, p1, p2, gamma,
                     beta, W2, b2, out);
}

// Round 8
// 685.031 us; speedup vs baseline: 1.3279x; 1.0468x over previous
//
#include <hip/hip_runtime.h>
#include <hip/hip_bf16.h>

#define T_STEPS 1000
#define BATCH   256
#define IN_C    32
#define HID     128
#define OUT_C   10

typedef __fp16 h2_t __attribute__((ext_vector_type(2)));

__device__ __forceinline__ float dot2f(uint32_t w, uint32_t a, float acc) {
#if __has_builtin(__builtin_amdgcn_fdot2)
  return __builtin_amdgcn_fdot2(__builtin_bit_cast(h2_t, a),
                                __builtin_bit_cast(h2_t, w), acc, false);
#else
  h2_t av = __builtin_bit_cast(h2_t, a);
  h2_t wv = __builtin_bit_cast(h2_t, w);
  return acc + (float)av[0] * (float)wv[0] + (float)av[1] * (float)wv[1];
#endif
}

__device__ __forceinline__ uint32_t pack_f16(float a, float b) {
#if __has_builtin(__builtin_amdgcn_cvt_pkrtz)
  auto p = __builtin_amdgcn_cvt_pkrtz(a, b);
  return __builtin_bit_cast(uint32_t, p);
#else
  h2_t p; p[0] = (__fp16)a; p[1] = (__fp16)b;
  return __builtin_bit_cast(uint32_t, p);
#endif
}

// quad_perm DPP lane swaps (VALU-speed, quad-local only)
__device__ __forceinline__ float dpp_xor1(float x) {   // lane ^= 1 within quad
  return __builtin_bit_cast(float, __builtin_amdgcn_update_dpp(
      0, __builtin_bit_cast(int, x), 0xB1, 0xF, 0xF, true));
}
__device__ __forceinline__ float dpp_xor2(float x) {   // lane ^= 2 within quad
  return __builtin_bit_cast(float, __builtin_amdgcn_update_dpp(
      0, __builtin_bit_cast(int, x), 0x4E, 0xF, 0xF, true));
}

__device__ __forceinline__ float fast_tanh(float x) {
  // tanh via exp2: a=2*log2(e)*x. Lower clamp unneeded (exp2(-big)=0 -> -1
  // exactly); upper clamp guards the inf path (inf-1)*rcp(inf+1)=NaN.
  float a = fminf(x * 2.88539008178f, 126.f);
#if __has_builtin(__builtin_amdgcn_exp2f)
  float t = __builtin_amdgcn_exp2f(a);
#else
  float t = exp2f(a);
#endif
#if __has_builtin(__builtin_amdgcn_rcpf)
  float r = __builtin_amdgcn_rcpf(t + 1.f);
#else
  float r = 1.f / (t + 1.f);
#endif
  return (t - 1.f) * r;
}

// block barrier WITHOUT draining vmcnt: dW prefetch stays in flight.
#define WG_BARRIER() asm volatile("s_waitcnt lgkmcnt(0)\n\ts_barrier" ::: "memory")

// ---------------- kernel 1: Euler-Maruyama SDE per trajectory ----------------
// block b = trajectory; 512 threads (8 waves -> 2 per SIMD):
//   j = tid>>2 (hidden unit), s = (tid>>1)&1 (f vs g), h = tid&1 (k-half)
// R4 structure (measured floor of this decomposition family):
//   - dt computed in prologue (k_dt kernel folded in)
//   - all LDS writes unguarded (quad lanes write identical values: benign)
//   - phase-2 f<->g exchange pre-tanh; dws hoisted off the z chain
__global__ __launch_bounds__(512) void k_sde(
    const float* __restrict__ times,
    const float* __restrict__ x0, const float* __restrict__ dW,
    const int* __restrict__ fidx,
    const float* __restrict__ Winit, const float* __restrict__ binit,
    const float* __restrict__ Wf1, const float* __restrict__ bf1,
    const float* __restrict__ Wf2, const float* __restrict__ bf2,
    const float* __restrict__ Wg1, const float* __restrict__ bg1,
    const float* __restrict__ Wg2, const float* __restrict__ bg2,
    float* __restrict__ zf) {
  const int b = blockIdx.x;
  const int tid = threadIdx.x;
  const int j = tid >> 2;
  const int s = (tid >> 1) & 1;
  const int h = tid & 1;

  __shared__ alignas(16) uint4 zp4[16];   // z: 128 f16, chunk m = elems 8m..8m+7
  __shared__ alignas(16) uint4 hb[36];    // hf = hb[0..16), hg = hb[18..34)
  __shared__ float sred[512];             // prologue dt-reduce only

  // ---- prologue A: dt = max(min(diff(times)), 0.001), per-block reduce ----
  {
    float d0 = (tid < T_STEPS - 1) ? times[tid + 1] - times[tid] : 1e30f;
    int i2 = tid + 512;
    float d1 = (i2 < T_STEPS - 1) ? times[i2 + 1] - times[i2] : 1e30f;
    sred[tid] = fminf(d0, d1);
    __syncthreads();
    for (int off = 256; off > 0; off >>= 1) {
      if (tid < off) sred[tid] = fminf(sred[tid], sred[tid + off]);
      __syncthreads();
    }
  }
  const float dt  = fmaxf(sred[0], 0.001f);
  const float sdt = sqrtf(dt);

  // ---- prologue B: weight-stationary packing, interleaved chunk order ----
  // read c pulls chunk m=2c+h holding elements 8m..8m+7 (pairs 4m..4m+3)
  const float* M1 = s ? Wg1 : Wf1;
  const float* M2 = s ? Wg2 : Wf2;
  uint32_t wA[32], wB[32];
#pragma unroll
  for (int c = 0; c < 8; ++c) {
    int k0 = (2 * c + h) * 8;
#pragma unroll
    for (int d = 0; d < 4; ++d) {
      wA[4 * c + d] = pack_f16(M1[(k0 + 2 * d) * HID + j], M1[(k0 + 2 * d + 1) * HID + j]);
      wB[4 * c + d] = pack_f16(M2[(k0 + 2 * d) * HID + j], M2[(k0 + 2 * d + 1) * HID + j]);
    }
  }
  const float bias1 = h ? 0.f : (s ? bg1 : bf1)[j];
  const float bias2 = h ? 0.f : (s ? bg2 : bf2)[j];

  // z0 = x0 @ Winit + binit  (replicated across the 4 (s,h) lanes of j)
  float z = binit[j];
#pragma unroll
  for (int i = 0; i < IN_C; ++i)
    z = fmaf(x0[b * IN_C + i], Winit[i * HID + j], z);

  __fp16* zh = (__fp16*)zp4;
  zh[j] = (__fp16)z;   // all 4 quad lanes write the same value: benign

  const int nsteps = fidx[b];  // in [0, T-1]

  const float* dwp = dW + (size_t)b * HID + j;
  const size_t sBH = (size_t)BATCH * HID;
  float dwA = dwp[0];
  float dwB = dwp[sBH];
  float dwC = dwp[2 * sBH];

  const uint4* hp4 = hb + s * 18;
  __fp16* hdst     = (__fp16*)(hb + s * 18);

  WG_BARRIER();

  for (int t = 0; t < nsteps; ++t) {
    float dws = sdt * dwA;     // hoisted off the z chain
    dwA = dwB;
    dwB = dwC;
    int tn = t + 3;
    if (tn > T_STEPS - 2) tn = T_STEPS - 2;
    dwC = dwp[(size_t)tn * sBH];  // prefetch 3 ahead, survives barriers

    // ---- phase 1: layer 1 half-dot over interleaved k-chunks ----
    float a0 = bias1, a1 = 0.f, a2 = 0.f, a3 = 0.f;
#pragma unroll
    for (int c = 0; c < 8; ++c) {
      uint4 v = zp4[2 * c + h];
      a0 = dot2f(wA[4 * c + 0], v.x, a0);
      a1 = dot2f(wA[4 * c + 1], v.y, a1);
      a2 = dot2f(wA[4 * c + 2], v.z, a2);
      a3 = dot2f(wA[4 * c + 3], v.w, a3);
    }
    float p = (a0 + a1) + (a2 + a3);
    p += dpp_xor1(p);                   // combine k-halves (VALU DPP)
    float h1 = fast_tanh(p);
    hdst[j] = (__fp16)h1;               // both h-lanes write same value: benign
    WG_BARRIER();

    // ---- phase 2: layer 2 half-dot ----
    float q0 = bias2, q1 = 0.f, q2 = 0.f, q3 = 0.f;
#pragma unroll
    for (int c = 0; c < 8; ++c) {
      uint4 v = hp4[2 * c + h];
      q0 = dot2f(wB[4 * c + 0], v.x, q0);
      q1 = dot2f(wB[4 * c + 1], v.y, q1);
      q2 = dot2f(wB[4 * c + 2], v.z, q2);
      q3 = dot2f(wB[4 * c + 3], v.w, q3);
    }
    float qs = (q0 + q1) + (q2 + q3);
    qs += dpp_xor1(qs);                 // combine k-halves
    float oth = dpp_xor2(qs);           // f<->g pre-activation exchange
    float fpre = s ? oth : qs;          // f output (no outer tanh)
    float gpre = s ? qs : oth;          // g pre-activation (tanh-bounded)
    z = fmaf(fpre, dt, fmaf(fast_tanh(gpre), dws, z));
    zh[j] = (__fp16)z;                  // all 4 quad lanes write same value
    WG_BARRIER();
  }

  if ((tid & 3) == 0) zf[b * HID + j] = z;
}

// ---------------- kernel 2a: h = zf @ W1 + b1, per-block column partial stats --
__global__ __launch_bounds__(256) void k_ro1(const float* __restrict__ zf,
                                             const float* __restrict__ W1,
                                             const float* __restrict__ b1,
                                             float* __restrict__ hbuf,
                                             float* __restrict__ p1,
                                             float* __restrict__ p2) {
  int blk = blockIdx.x;  // 32 blocks x 8 rows
  int tid = threadIdx.x;
  int j = tid & 127, half = tid >> 7;
  int b0 = blk * 8 + half * 4;
  float acc[4];
  float bj = b1[j];
#pragma unroll
  for (int r = 0; r < 4; ++r) acc[r] = bj;
  for (int i = 0; i < HID; ++i) {
    float w = W1[i * HID + j];
#pragma unroll
    for (int r = 0; r < 4; ++r)
      acc[r] = fmaf(zf[(b0 + r) * HID + i], w, acc[r]);
  }
  float s1 = 0.f, s2 = 0.f;
#pragma unroll
  for (int r = 0; r < 4; ++r) {
    hbuf[(b0 + r) * HID + j] = acc[r];
    s1 += acc[r];
    s2 = fmaf(acc[r], acc[r], s2);
  }
  __shared__ float q1[2][128], q2[2][128];
  q1[half][j] = s1;
  q2[half][j] = s2;
  __syncthreads();
  if (tid < 128) {
    p1[blk * HID + tid] = q1[0][tid] + q1[1][tid];
    p2[blk * HID + tid] = q2[0][tid] + q2[1][tid];
  }
}

// ---------------- kernel 2b: BN + ReLU + W2 readout (4 blocks x 640 outputs) --
__global__ __launch_bounds__(640) void k_ro2(
    const float* __restrict__ hbuf, const float* __restrict__ p1,
    const float* __restrict__ p2, const float* __restrict__ gamma,
    const float* __restrict__ beta, const float* __restrict__ W2,
    const float* __restrict__ b2, float* __restrict__ out) {
  __shared__ float sa[128], sc[128];
  int tid = threadIdx.x;
  if (tid < 128) {
    float m = 0.f, q = 0.f;
    for (int blk = 0; blk < 32; ++blk) {
      m += p1[blk * HID + tid];
      q += p2[blk * HID + tid];
    }
    m *= (1.f / BATCH);
    q *= (1.f / BATCH);
    float var = q - m * m;
    float r = rsqrtf(var + 1e-5f);
    float a = gamma[tid] * r;
    sa[tid] = a;
    sc[tid] = beta[tid] - m * a;
  }
  __syncthreads();
  int idx = blockIdx.x * 640 + tid;
  if (idx < BATCH * OUT_C) {
    int b = idx / OUT_C;
    int o = idx - b * OUT_C;
    float acc = b2[o];
    for (int jj = 0; jj < HID; ++jj) {
      float hn = fmaxf(fmaf(sa[jj], hbuf[b * HID + jj], sc[jj]), 0.f);
      acc = fmaf(hn, W2[jj * OUT_C + o], acc);
    }
    out[idx] = acc;
  }
}

extern "C" void kernel_launch(void* const* d_in, const int* in_sizes, int n_in,
                              void* d_out, int out_size, void* d_ws, size_t ws_size,
                              hipStream_t stream) {
  const float* times = (const float*)d_in[0];
  const float* x0    = (const float*)d_in[1];
  const float* dW    = (const float*)d_in[2];
  const int*   fidx  = (const int*)d_in[3];
  const float* Winit = (const float*)d_in[4];
  const float* binit = (const float*)d_in[5];
  const float* Wf1 = (const float*)d_in[6];
  const float* bf1 = (const float*)d_in[7];
  const float* Wf2 = (const float*)d_in[8];
  const float* bf2 = (const float*)d_in[9];
  const float* Wg1 = (const float*)d_in[10];
  const float* bg1 = (const float*)d_in[11];
  const float* Wg2 = (const float*)d_in[12];
  const float* bg2 = (const float*)d_in[13];
  const float* W1  = (const float*)d_in[14];
  const float* b1  = (const float*)d_in[15];
  const float* gamma = (const float*)d_in[16];
  const float* beta  = (const float*)d_in[17];
  const float* W2  = (const float*)d_in[18];
  const float* b2  = (const float*)d_in[19];

  float* wsf  = (float*)d_ws;
  float* zf   = wsf + 16;                  // 256*128
  float* hbuf = zf + BATCH * HID;          // 256*128
  float* p1   = hbuf + BATCH * HID;        // 32*128
  float* p2   = p1 + 32 * HID;             // 32*128
  float* out  = (float*)d_out;

  hipLaunchKernelGGL(k_sde, dim3(BATCH), dim3(512), 0, stream, times, x0, dW,
                     fidx, Winit, binit, Wf1, bf1, Wf2, bf2, Wg1, bg1, Wg2, bg2,
                     zf);
  hipLaunchKernelGGL(k_ro1, dim3(32), dim3(256), 0, stream, zf, W1, b1, hbuf,
                     p1, p2);
  hipLaunchKernelGGL(k_ro2, dim3(4), dim3(640), 0, stream, hbuf, p1, p2, gamma,
                     beta, W2, b2, out);
}